// Round 1
// baseline (653.079 us; speedup 1.0000x reference)
//
#include <hip/hip_runtime.h>
#include <stdint.h>

typedef __attribute__((ext_vector_type(8))) short short8;   // 8 bf16 operand frag
typedef __attribute__((ext_vector_type(4))) float f32x4;    // MFMA accumulator
typedef __attribute__((ext_vector_type(4))) unsigned short us4;

#define BM 128
#define BN 128
#define BKK 32

// ---- bf16 helpers (RNE) ----
__device__ inline unsigned short f2bf(float x) {
  unsigned int u = __float_as_uint(x);
  unsigned int r = (u + 0x7fffu + ((u >> 16) & 1u)) >> 16;
  return (unsigned short)r;
}
__device__ inline float bf2f(unsigned short h) {
  return __uint_as_float(((unsigned int)h) << 16);
}

// ---- fp32 -> (hi, lo) bf16 split, vectorized x4 ----
__global__ void k_conv_hilo(const float* __restrict__ in, unsigned short* __restrict__ hi,
                            unsigned short* __restrict__ lo, long n4) {
  long i = (long)blockIdx.x * blockDim.x + threadIdx.x;
  if (i >= n4) return;
  float4 v = ((const float4*)in)[i];
  float vv[4] = {v.x, v.y, v.z, v.w};
  us4 h, l;
#pragma unroll
  for (int j = 0; j < 4; ++j) {
    unsigned short hb = f2bf(vv[j]);
    h[j] = hb;
    l[j] = f2bf(vv[j] - bf2f(hb));
  }
  *(us4*)(hi + i * 4) = h;
  *(us4*)(lo + i * 4) = l;
}

// ---- V [K x D] fp32  ->  VT [D x K] bf16 (per batch) ----
__global__ void k_transpose_bf(const float* __restrict__ V, unsigned short* __restrict__ VT,
                               int Kn, int Dn) {
  __shared__ unsigned short t[64][65];
  const int b = blockIdx.z;
  const int k0 = blockIdx.x * 64, d0 = blockIdx.y * 64;
  const int c = threadIdx.x & 63, rr = threadIdx.x >> 6;
  const float* pV = V + (long)b * Kn * Dn;
  unsigned short* pT = VT + (long)b * Dn * Kn;
#pragma unroll
  for (int i = 0; i < 16; ++i) {
    int r = rr + i * 4;
    t[r][c] = f2bf(pV[(long)(k0 + r) * Dn + d0 + c]);
  }
  __syncthreads();
#pragma unroll
  for (int i = 0; i < 16; ++i) {
    int r = rr + i * 4;
    pT[(long)(d0 + r) * Kn + k0 + c] = t[c][r];
  }
}

// ---- GEMM C[M,N] = A[M,Kin] * B[N,Kin]^T, bf16 MFMA, fp32 out.
// SPLIT==3: A,B given as hi/lo pairs; acc += Ah*Bh + Ah*Bl + Al*Bh (near-fp32).
// SPLIT==1: plain bf16 (Al/Bl ignored).
// Layouts (m89/m91-verified): A frag lane=m+16*quad holds A[m][quad*8+j];
// B frag lane=n+16*quad holds B[quad*8+j][n]; C: col=lane&15, row=quad*4+reg.
template <int SPLIT>
__launch_bounds__(256)
__global__ void k_gemm_bt(const unsigned short* __restrict__ Ah,
                          const unsigned short* __restrict__ Al,
                          const unsigned short* __restrict__ Bh,
                          const unsigned short* __restrict__ Bl,
                          float* __restrict__ C,
                          int N, int Kin, long sA, long sB, long sC) {
  __shared__ unsigned short sAh[BM * BKK];
  __shared__ unsigned short sBh[BN * BKK];
  __shared__ unsigned short sAl[(SPLIT == 3) ? BM * BKK : 16];
  __shared__ unsigned short sBl[(SPLIT == 3) ? BN * BKK : 16];

  const int b = blockIdx.z;
  const int tm = blockIdx.y, tn = blockIdx.x;
  const int tid = threadIdx.x;
  const int lane = tid & 63;
  const int wave = tid >> 6;
  const int wm = (wave & 1) * 64, wn = (wave >> 1) * 64;

  const unsigned short* pAh = Ah + b * sA + (long)tm * BM * Kin;
  const unsigned short* pBh = Bh + b * sB + (long)tn * BN * Kin;
  const unsigned short* pAl = (SPLIT == 3) ? (Al + b * sA + (long)tm * BM * Kin) : pAh;
  const unsigned short* pBl = (SPLIT == 3) ? (Bl + b * sB + (long)tn * BN * Kin) : pBh;
  float* pC = C + b * sC;

  // staging: chunk c (of 16B) covers row c>>2, k-offset (c&3)*8; LDS offset c*16B
  const int c0 = tid, c1 = tid + 256;
  const long ga0 = (long)(c0 >> 2) * Kin + (c0 & 3) * 8;
  const long ga1 = (long)(c1 >> 2) * Kin + (c1 & 3) * 8;

  f32x4 acc[4][4];
#pragma unroll
  for (int i = 0; i < 4; ++i)
#pragma unroll
    for (int j = 0; j < 4; ++j)
#pragma unroll
      for (int r = 0; r < 4; ++r) acc[i][j][r] = 0.f;

  const int mrow = wm + (lane & 15);
  const int nrow = wn + (lane & 15);
  const int kq = (lane >> 4) * 8;

  const int nk = Kin / BKK;
  for (int kt = 0; kt < nk; ++kt) {
    const long kb = (long)kt * BKK;
    short8 va0 = *(const short8*)(pAh + ga0 + kb);
    short8 va1 = *(const short8*)(pAh + ga1 + kb);
    short8 vb0 = *(const short8*)(pBh + ga0 + kb);
    short8 vb1 = *(const short8*)(pBh + ga1 + kb);
    short8 wa0, wa1, wb0, wb1;
    if constexpr (SPLIT == 3) {
      wa0 = *(const short8*)(pAl + ga0 + kb);
      wa1 = *(const short8*)(pAl + ga1 + kb);
      wb0 = *(const short8*)(pBl + ga0 + kb);
      wb1 = *(const short8*)(pBl + ga1 + kb);
    }
    __syncthreads();
    *(short8*)&sAh[c0 * 8] = va0;
    *(short8*)&sAh[c1 * 8] = va1;
    *(short8*)&sBh[c0 * 8] = vb0;
    *(short8*)&sBh[c1 * 8] = vb1;
    if constexpr (SPLIT == 3) {
      *(short8*)&sAl[c0 * 8] = wa0;
      *(short8*)&sAl[c1 * 8] = wa1;
      *(short8*)&sBl[c0 * 8] = wb0;
      *(short8*)&sBl[c1 * 8] = wb1;
    }
    __syncthreads();

    short8 afh[4], bfh[4], afl[4], bfl[4];
#pragma unroll
    for (int i = 0; i < 4; ++i) {
      afh[i] = *(const short8*)&sAh[(mrow + i * 16) * BKK + kq];
      bfh[i] = *(const short8*)&sBh[(nrow + i * 16) * BKK + kq];
      if constexpr (SPLIT == 3) {
        afl[i] = *(const short8*)&sAl[(mrow + i * 16) * BKK + kq];
        bfl[i] = *(const short8*)&sBl[(nrow + i * 16) * BKK + kq];
      }
    }
#pragma unroll
    for (int i = 0; i < 4; ++i)
#pragma unroll
      for (int j = 0; j < 4; ++j) {
        acc[i][j] = __builtin_amdgcn_mfma_f32_16x16x32_bf16(afh[i], bfh[j], acc[i][j], 0, 0, 0);
        if constexpr (SPLIT == 3) {
          acc[i][j] = __builtin_amdgcn_mfma_f32_16x16x32_bf16(afh[i], bfl[j], acc[i][j], 0, 0, 0);
          acc[i][j] = __builtin_amdgcn_mfma_f32_16x16x32_bf16(afl[i], bfh[j], acc[i][j], 0, 0, 0);
        }
      }
  }

  const int crow0 = tm * BM + wm + (lane >> 4) * 4;
  const int ccol0 = tn * BN + wn + (lane & 15);
#pragma unroll
  for (int i = 0; i < 4; ++i)
#pragma unroll
    for (int j = 0; j < 4; ++j)
#pragma unroll
      for (int r = 0; r < 4; ++r)
        pC[(long)(crow0 + i * 16 + r) * N + (ccol0 + j * 16)] = acc[i][j][r];
}

// ---- per-column (k) online softmax stats over a q-chunk of 256 ----
__global__ void k_stats_partial(const float* __restrict__ S, float2* __restrict__ ps,
                                int Qn, int Kn) {
  const int b = blockIdx.z, qc = blockIdx.y;
  const int k = blockIdx.x * 256 + threadIdx.x;
  const float* p = S + (long)b * Qn * Kn + (long)qc * 256 * Kn + k;
  float m = -3.0e38f, l = 0.f;
  for (int q = 0; q < 256; ++q) {
    float s = p[(long)q * Kn];
    float mn = fmaxf(m, s);
    l = l * __expf(m - mn) + __expf(s - mn);
    m = mn;
  }
  ps[((long)(b * 8 + qc)) * Kn + k] = make_float2(m, l);
}

__global__ void k_stats_combine(const float2* __restrict__ ps, float2* __restrict__ st, int Kn) {
  const long i = (long)blockIdx.x * blockDim.x + threadIdx.x;  // over nb*Kn
  const int b = (int)(i / Kn), k = (int)(i % Kn);
  float M = -3.0e38f;
#pragma unroll
  for (int j = 0; j < 8; ++j) M = fmaxf(M, ps[((long)(b * 8 + j)) * Kn + k].x);
  float L = 0.f;
#pragma unroll
  for (int j = 0; j < 8; ++j) {
    float2 v = ps[((long)(b * 8 + j)) * Kn + k];
    L += v.y * __expf(v.x - M);
  }
  st[i] = make_float2(M, 1.0f / L);
}

// ---- P = exp(S - M_k) * invL_k -> bf16, vectorized x4 ----
__global__ void k_pcomp(const float* __restrict__ S, const float2* __restrict__ st,
                        unsigned short* __restrict__ P) {
  const long i = (long)blockIdx.x * blockDim.x + threadIdx.x;  // 4 elems each
  const long r = i >> 9;               // row = b*2048 + q  (2048/4 = 512 thr/row)
  const int kb = (int)(i & 511) * 4;
  const int b = (int)(r >> 11);
  float4 s = *(const float4*)(S + r * 2048 + kb);
  const float2* sp = st + (long)b * 2048 + kb;
  float2 s0 = sp[0], s1 = sp[1], s2 = sp[2], s3 = sp[3];
  us4 o;
  o[0] = f2bf(__expf(s.x - s0.x) * s0.y);
  o[1] = f2bf(__expf(s.y - s1.x) * s1.y);
  o[2] = f2bf(__expf(s.z - s2.x) * s2.y);
  o[3] = f2bf(__expf(s.w - s3.x) * s3.y);
  *(us4*)(P + r * 2048 + kb) = o;
}

extern "C" void kernel_launch(void* const* d_in, const int* in_sizes, int n_in,
                              void* d_out, int out_size, void* d_ws, size_t ws_size,
                              hipStream_t stream) {
  const float* Q = (const float*)d_in[0];
  const float* Kp = (const float*)d_in[1];
  const float* V = (const float*)d_in[2];
  float* out = (float*)d_out;

  constexpr int Bb = 8, Qn = 2048, Kn = 2048, Dn = 1024;
  constexpr long QD = (long)Qn * Dn, KD = (long)Kn * Dn, QK = (long)Qn * Kn, DK = (long)Dn * Kn;

  // per-batch workspace need (bytes)
  const size_t per = 4 * (size_t)(QD * 2)   // qhi,qlo,khi,klo
                   + (size_t)(DK * 2)       // vt
                   + (size_t)(QK * 4)       // S
                   + (size_t)(QK * 2)       // P
                   + (size_t)(8 * Kn * 8)   // partial stats
                   + (size_t)(Kn * 8);      // final stats
  int cb = 8;
  while (cb > 1 && (size_t)cb * per > ws_size) cb >>= 1;

  char* w = (char*)d_ws;
  unsigned short* qhi = (unsigned short*)w; w += (size_t)cb * QD * 2;
  unsigned short* qlo = (unsigned short*)w; w += (size_t)cb * QD * 2;
  unsigned short* khi = (unsigned short*)w; w += (size_t)cb * KD * 2;
  unsigned short* klo = (unsigned short*)w; w += (size_t)cb * KD * 2;
  unsigned short* vt  = (unsigned short*)w; w += (size_t)cb * DK * 2;
  float* S            = (float*)w;          w += (size_t)cb * QK * 4;
  unsigned short* P   = (unsigned short*)w; w += (size_t)cb * QK * 2;
  float2* ps          = (float2*)w;         w += (size_t)cb * 8 * Kn * 8;
  float2* st          = (float2*)w;

  for (int b0 = 0; b0 < Bb; b0 += cb) {
    int nb = (cb < Bb - b0) ? cb : (Bb - b0);
    long n4 = (long)nb * QD / 4;
    k_conv_hilo<<<(int)(n4 / 256), 256, 0, stream>>>(Q + b0 * QD, qhi, qlo, n4);
    k_conv_hilo<<<(int)(n4 / 256), 256, 0, stream>>>(Kp + b0 * KD, khi, klo, n4);
    k_transpose_bf<<<dim3(Kn / 64, Dn / 64, nb), 256, 0, stream>>>(V + b0 * KD, vt, Kn, Dn);
    k_gemm_bt<3><<<dim3(Kn / 128, Qn / 128, nb), 256, 0, stream>>>(
        qhi, qlo, khi, klo, S, Kn, Dn, QD, KD, QK);
    k_stats_partial<<<dim3(Kn / 256, Qn / 256, nb), 256, 0, stream>>>(S, ps, Qn, Kn);
    k_stats_combine<<<nb * Kn / 256, 256, 0, stream>>>(ps, st, Kn);
    k_pcomp<<<(int)((long)nb * QK / 4 / 256), 256, 0, stream>>>(S, st, P);
    k_gemm_bt<1><<<dim3(Dn / 128, Qn / 128, nb), 256, 0, stream>>>(
        P, P, vt, vt, out + b0 * QD, Dn, Kn, QK, DK, QD);
  }
}

// Round 2
// 615.979 us; speedup vs baseline: 1.0602x; 1.0602x over previous
//
#include <hip/hip_runtime.h>
#include <stdint.h>

typedef __attribute__((ext_vector_type(8))) short short8;   // 8 bf16 operand frag
typedef __attribute__((ext_vector_type(4))) float f32x4;    // MFMA accumulator
typedef __attribute__((ext_vector_type(4))) unsigned short us4;

#define BM 128
#define BN 128
#define BKK 32

// ---- bf16 helpers (RNE) ----
__device__ inline unsigned short f2bf(float x) {
  unsigned int u = __float_as_uint(x);
  unsigned int r = (u + 0x7fffu + ((u >> 16) & 1u)) >> 16;
  return (unsigned short)r;
}
__device__ inline float bf2f(unsigned short h) {
  return __uint_as_float(((unsigned int)h) << 16);
}

// ---- async global->LDS, 16B per lane (m97 pattern) ----
__device__ inline void ld16(const unsigned short* g, unsigned short* l) {
  __builtin_amdgcn_global_load_lds(
      (const __attribute__((address_space(1))) unsigned int*)g,
      (__attribute__((address_space(3))) unsigned int*)l, 16, 0, 0);
}

// ---- fp32 -> (hi, lo) bf16 split, vectorized x4 ----
__global__ void k_conv_hilo(const float* __restrict__ in, unsigned short* __restrict__ hi,
                            unsigned short* __restrict__ lo, long n4) {
  long i = (long)blockIdx.x * blockDim.x + threadIdx.x;
  if (i >= n4) return;
  float4 v = ((const float4*)in)[i];
  float vv[4] = {v.x, v.y, v.z, v.w};
  us4 h, l;
#pragma unroll
  for (int j = 0; j < 4; ++j) {
    unsigned short hb = f2bf(vv[j]);
    h[j] = hb;
    l[j] = f2bf(vv[j] - bf2f(hb));
  }
  *(us4*)(hi + i * 4) = h;
  *(us4*)(lo + i * 4) = l;
}

// ---- V [K x D] fp32  ->  VT [D x K] bf16 (per batch) ----
__global__ void k_transpose_bf(const float* __restrict__ V, unsigned short* __restrict__ VT,
                               int Kn, int Dn) {
  __shared__ unsigned short t[64][65];
  const int b = blockIdx.z;
  const int k0 = blockIdx.x * 64, d0 = blockIdx.y * 64;
  const int c = threadIdx.x & 63, rr = threadIdx.x >> 6;
  const float* pV = V + (long)b * Kn * Dn;
  unsigned short* pT = VT + (long)b * Dn * Kn;
#pragma unroll
  for (int i = 0; i < 16; ++i) {
    int r = rr + i * 4;
    t[r][c] = f2bf(pV[(long)(k0 + r) * Dn + d0 + c]);
  }
  __syncthreads();
#pragma unroll
  for (int i = 0; i < 16; ++i) {
    int r = rr + i * 4;
    pT[(long)(d0 + r) * Kn + k0 + c] = t[c][r];
  }
}

// ---- GEMM C[M,N] = A[M,Kin] * B[N,Kin]^T, bf16 MFMA, fp32 out.
// SPLIT==3: A,B as hi/lo pairs; acc += Ah*Bh + Ah*Bl + Al*Bh (near-fp32).
// SPLIT==1: plain bf16. STATS==1: also emit per-(wm-half) column max/sumexp
// partials over the tile's rows (for the q-axis softmax).
// Staging via global_load_lds(16B): LDS dest = tid*16 (lane-contiguous, the
// HW constraint); chunk c covers row c>>2, k-part (c&3)*8.
template <int SPLIT, int STATS>
__launch_bounds__(256)
__global__ void k_gemm_bt(const unsigned short* __restrict__ Ah,
                          const unsigned short* __restrict__ Al,
                          const unsigned short* __restrict__ Bh,
                          const unsigned short* __restrict__ Bl,
                          float* __restrict__ C, float2* __restrict__ ps,
                          int N, int Kin, long sA, long sB, long sC) {
  __shared__ unsigned short sAh[BM * BKK];
  __shared__ unsigned short sBh[BN * BKK];
  __shared__ unsigned short sAl[(SPLIT == 3) ? BM * BKK : 16];
  __shared__ unsigned short sBl[(SPLIT == 3) ? BN * BKK : 16];

  const int b = blockIdx.z;
  const int tm = blockIdx.y, tn = blockIdx.x;
  const int tid = threadIdx.x;
  const int lane = tid & 63;
  const int wave = tid >> 6;
  const int wm = (wave & 1) * 64, wn = (wave >> 1) * 64;

  const unsigned short* pAh = Ah + b * sA + (long)tm * BM * Kin;
  const unsigned short* pBh = Bh + b * sB + (long)tn * BN * Kin;
  const unsigned short* pAl = (SPLIT == 3) ? (Al + b * sA + (long)tm * BM * Kin) : pAh;
  const unsigned short* pBl = (SPLIT == 3) ? (Bl + b * sB + (long)tn * BN * Kin) : pBh;
  float* pC = C + b * sC;

  const int c0 = tid, c1 = tid + 256;
  const long ga0 = (long)(c0 >> 2) * Kin + (c0 & 3) * 8;
  const long ga1 = (long)(c1 >> 2) * Kin + (c1 & 3) * 8;

  f32x4 acc[4][4];
#pragma unroll
  for (int i = 0; i < 4; ++i)
#pragma unroll
    for (int j = 0; j < 4; ++j)
#pragma unroll
      for (int r = 0; r < 4; ++r) acc[i][j][r] = 0.f;

  const int mrow = wm + (lane & 15);
  const int nrow = wn + (lane & 15);
  const int kq = (lane >> 4) * 8;

  const int nk = Kin / BKK;
  for (int kt = 0; kt < nk; ++kt) {
    const long kb = (long)kt * BKK;
    __syncthreads();  // previous iter's LDS reads complete before overwrite
    ld16(pAh + ga0 + kb, &sAh[c0 * 8]);
    ld16(pAh + ga1 + kb, &sAh[c1 * 8]);
    ld16(pBh + ga0 + kb, &sBh[c0 * 8]);
    ld16(pBh + ga1 + kb, &sBh[c1 * 8]);
    if constexpr (SPLIT == 3) {
      ld16(pAl + ga0 + kb, &sAl[c0 * 8]);
      ld16(pAl + ga1 + kb, &sAl[c1 * 8]);
      ld16(pBl + ga0 + kb, &sBl[c0 * 8]);
      ld16(pBl + ga1 + kb, &sBl[c1 * 8]);
    }
    __syncthreads();  // compiler drains vmcnt before barrier -> LDS ready

    short8 afh[4], bfh[4], afl[4], bfl[4];
#pragma unroll
    for (int i = 0; i < 4; ++i) {
      afh[i] = *(const short8*)&sAh[(mrow + i * 16) * BKK + kq];
      bfh[i] = *(const short8*)&sBh[(nrow + i * 16) * BKK + kq];
      if constexpr (SPLIT == 3) {
        afl[i] = *(const short8*)&sAl[(mrow + i * 16) * BKK + kq];
        bfl[i] = *(const short8*)&sBl[(nrow + i * 16) * BKK + kq];
      }
    }
    // three independent sweeps -> 16-deep independent MFMA chains
#pragma unroll
    for (int i = 0; i < 4; ++i)
#pragma unroll
      for (int j = 0; j < 4; ++j)
        acc[i][j] = __builtin_amdgcn_mfma_f32_16x16x32_bf16(afh[i], bfh[j], acc[i][j], 0, 0, 0);
    if constexpr (SPLIT == 3) {
#pragma unroll
      for (int i = 0; i < 4; ++i)
#pragma unroll
        for (int j = 0; j < 4; ++j)
          acc[i][j] = __builtin_amdgcn_mfma_f32_16x16x32_bf16(afh[i], bfl[j], acc[i][j], 0, 0, 0);
#pragma unroll
      for (int i = 0; i < 4; ++i)
#pragma unroll
        for (int j = 0; j < 4; ++j)
          acc[i][j] = __builtin_amdgcn_mfma_f32_16x16x32_bf16(afl[i], bfh[j], acc[i][j], 0, 0, 0);
    }
  }

  const int crow0 = tm * BM + wm + (lane >> 4) * 4;
  const int ccol0 = tn * BN + wn + (lane & 15);
#pragma unroll
  for (int i = 0; i < 4; ++i)
#pragma unroll
    for (int j = 0; j < 4; ++j)
#pragma unroll
      for (int r = 0; r < 4; ++r)
        pC[(long)(crow0 + i * 16 + r) * N + (ccol0 + j * 16)] = acc[i][j][r];

  if constexpr (STATS) {
    // per-wave column stats over this wave's 64 rows; cols = tn*BN+wn+j*16+lane&15
#pragma unroll
    for (int j = 0; j < 4; ++j) {
      float m = -3.0e38f;
#pragma unroll
      for (int i = 0; i < 4; ++i)
#pragma unroll
        for (int r = 0; r < 4; ++r) m = fmaxf(m, acc[i][j][r]);
      m = fmaxf(m, __shfl_xor(m, 16, 64));
      m = fmaxf(m, __shfl_xor(m, 32, 64));
      float l = 0.f;
#pragma unroll
      for (int i = 0; i < 4; ++i)
#pragma unroll
        for (int r = 0; r < 4; ++r) l += __expf(acc[i][j][r] - m);
      l += __shfl_xor(l, 16, 64);
      l += __shfl_xor(l, 32, 64);
      if (lane < 16) {
        int col = tn * BN + wn + j * 16 + lane;
        ps[((long)(b * 32 + tm * 2 + (wave & 1))) * N + col] = make_float2(m, l);
      }
    }
  }
}

// ---- combine 32 per-tile partials -> (M_k, 1/L_k) ----
__global__ void k_stats_combine(const float2* __restrict__ ps, float2* __restrict__ st, int Kn) {
  const long i = (long)blockIdx.x * blockDim.x + threadIdx.x;  // over nb*Kn
  const int b = (int)(i / Kn), k = (int)(i % Kn);
  float M = -3.0e38f;
#pragma unroll
  for (int j = 0; j < 32; ++j) M = fmaxf(M, ps[((long)(b * 32 + j)) * Kn + k].x);
  float L = 0.f;
#pragma unroll
  for (int j = 0; j < 32; ++j) {
    float2 v = ps[((long)(b * 32 + j)) * Kn + k];
    L += v.y * __expf(v.x - M);
  }
  st[i] = make_float2(M, 1.0f / L);
}

// ---- P = exp(S - M_k) * invL_k -> bf16, vectorized x4 ----
__global__ void k_pcomp(const float* __restrict__ S, const float2* __restrict__ st,
                        unsigned short* __restrict__ P) {
  const long i = (long)blockIdx.x * blockDim.x + threadIdx.x;  // 4 elems each
  const long r = i >> 9;               // row = b*2048 + q  (2048/4 = 512 thr/row)
  const int kb = (int)(i & 511) * 4;
  const int b = (int)(r >> 11);
  float4 s = *(const float4*)(S + r * 2048 + kb);
  const float2* sp = st + (long)b * 2048 + kb;
  float2 s0 = sp[0], s1 = sp[1], s2 = sp[2], s3 = sp[3];
  us4 o;
  o[0] = f2bf(__expf(s.x - s0.x) * s0.y);
  o[1] = f2bf(__expf(s.y - s1.x) * s1.y);
  o[2] = f2bf(__expf(s.z - s2.x) * s2.y);
  o[3] = f2bf(__expf(s.w - s3.x) * s3.y);
  *(us4*)(P + r * 2048 + kb) = o;
}

extern "C" void kernel_launch(void* const* d_in, const int* in_sizes, int n_in,
                              void* d_out, int out_size, void* d_ws, size_t ws_size,
                              hipStream_t stream) {
  const float* Q = (const float*)d_in[0];
  const float* Kp = (const float*)d_in[1];
  const float* V = (const float*)d_in[2];
  float* out = (float*)d_out;

  constexpr int Bb = 8, Qn = 2048, Kn = 2048, Dn = 1024;
  constexpr long QD = (long)Qn * Dn, KD = (long)Kn * Dn, QK = (long)Qn * Kn, DK = (long)Dn * Kn;

  // per-batch workspace need (bytes)
  const size_t per = 4 * (size_t)(QD * 2)   // qhi,qlo,khi,klo
                   + (size_t)(DK * 2)       // vt
                   + (size_t)(QK * 4)       // S
                   + (size_t)(QK * 2)       // P
                   + (size_t)(32 * Kn * 8)  // partial stats (32 slots)
                   + (size_t)(Kn * 8);      // final stats
  int cb = 8;
  while (cb > 1 && (size_t)cb * per > ws_size) cb >>= 1;

  char* w = (char*)d_ws;
  unsigned short* qhi = (unsigned short*)w; w += (size_t)cb * QD * 2;
  unsigned short* qlo = (unsigned short*)w; w += (size_t)cb * QD * 2;
  unsigned short* khi = (unsigned short*)w; w += (size_t)cb * KD * 2;
  unsigned short* klo = (unsigned short*)w; w += (size_t)cb * KD * 2;
  unsigned short* vt  = (unsigned short*)w; w += (size_t)cb * DK * 2;
  float* S            = (float*)w;          w += (size_t)cb * QK * 4;
  unsigned short* P   = (unsigned short*)w; w += (size_t)cb * QK * 2;
  float2* ps          = (float2*)w;         w += (size_t)cb * 32 * Kn * 8;
  float2* st          = (float2*)w;

  for (int b0 = 0; b0 < Bb; b0 += cb) {
    int nb = (cb < Bb - b0) ? cb : (Bb - b0);
    long n4 = (long)nb * QD / 4;
    k_conv_hilo<<<(int)(n4 / 256), 256, 0, stream>>>(Q + b0 * QD, qhi, qlo, n4);
    k_conv_hilo<<<(int)(n4 / 256), 256, 0, stream>>>(Kp + b0 * KD, khi, klo, n4);
    k_transpose_bf<<<dim3(Kn / 64, Dn / 64, nb), 256, 0, stream>>>(V + b0 * KD, vt, Kn, Dn);
    k_gemm_bt<3, 1><<<dim3(Kn / 128, Qn / 128, nb), 256, 0, stream>>>(
        qhi, qlo, khi, klo, S, ps, Kn, Dn, QD, KD, QK);
    k_stats_combine<<<nb * Kn / 256, 256, 0, stream>>>(ps, st, Kn);
    k_pcomp<<<(int)((long)nb * QK / 4 / 256), 256, 0, stream>>>(S, st, P);
    k_gemm_bt<1, 0><<<dim3(Dn / 128, Qn / 128, nb), 256, 0, stream>>>(
        P, P, vt, vt, out + b0 * QD, nullptr, Dn, Kn, QK, DK, QD);
  }
}

// Round 3
// 501.855 us; speedup vs baseline: 1.3013x; 1.2274x over previous
//
#include <hip/hip_runtime.h>
#include <stdint.h>

typedef _Float16 half8 __attribute__((ext_vector_type(8)));   // fp16 MFMA frag (4 VGPRs)
typedef __attribute__((ext_vector_type(4))) float f32x4;      // MFMA accumulator
typedef __attribute__((ext_vector_type(4))) unsigned short us4;
typedef __attribute__((ext_vector_type(8))) unsigned short us8;

#define BM 128
#define BN 128
#define BKK 32

__device__ inline unsigned short f2h(float x) {
  _Float16 h = (_Float16)x;                 // v_cvt_f16_f32, RNE
  return __builtin_bit_cast(unsigned short, h);
}

// ---- async global->LDS, 16B per lane (m97 pattern) ----
__device__ inline void ld16(const unsigned short* g, unsigned short* l) {
  __builtin_amdgcn_global_load_lds(
      (const __attribute__((address_space(1))) unsigned int*)g,
      (__attribute__((address_space(3))) unsigned int*)l, 16, 0, 0);
}

// ---- fp32 -> fp16 cast, 8 elems/thread ----
__global__ void k_cast16(const float* __restrict__ in, unsigned short* __restrict__ o, long n8) {
  long i = (long)blockIdx.x * blockDim.x + threadIdx.x;
  if (i >= n8) return;
  float4 a = ((const float4*)in)[i * 2];
  float4 b = ((const float4*)in)[i * 2 + 1];
  us8 h;
  h[0] = f2h(a.x); h[1] = f2h(a.y); h[2] = f2h(a.z); h[3] = f2h(a.w);
  h[4] = f2h(b.x); h[5] = f2h(b.y); h[6] = f2h(b.z); h[7] = f2h(b.w);
  *(us8*)(o + i * 8) = h;
}

// ---- V [K x D] fp32  ->  VT [D x K] fp16 (per batch) ----
__global__ void k_transpose16(const float* __restrict__ V, unsigned short* __restrict__ VT,
                              int Kn, int Dn) {
  __shared__ unsigned short t[64][65];
  const int b = blockIdx.z;
  const int k0 = blockIdx.x * 64, d0 = blockIdx.y * 64;
  const int c = threadIdx.x & 63, rr = threadIdx.x >> 6;
  const float* pV = V + (long)b * Kn * Dn;
  unsigned short* pT = VT + (long)b * Dn * Kn;
#pragma unroll
  for (int i = 0; i < 16; ++i) {
    int r = rr + i * 4;
    t[r][c] = f2h(pV[(long)(k0 + r) * Dn + d0 + c]);
  }
  __syncthreads();
#pragma unroll
  for (int i = 0; i < 16; ++i) {
    int r = rr + i * 4;
    pT[(long)(d0 + r) * Kn + k0 + c] = t[c][r];
  }
}

// ---- GEMM C[M,N] = A[M,Kin] * B[N,Kin]^T, fp16 MFMA, fp32 out.
// STATS==1: also emit per-(tile,wm-half) column max/sumexp partials over the
// tile's 64 rows (for the q-axis softmax). m97-structure K-loop.
template <int STATS>
__launch_bounds__(256)
__global__ void k_gemm_bt(const unsigned short* __restrict__ A,
                          const unsigned short* __restrict__ B,
                          float* __restrict__ C, float2* __restrict__ ps,
                          int N, int Kin, long sA, long sB, long sC) {
  __shared__ unsigned short sA_[BM * BKK];
  __shared__ unsigned short sB_[BN * BKK];

  const int b = blockIdx.z;
  const int tm = blockIdx.y, tn = blockIdx.x;
  const int tid = threadIdx.x;
  const int lane = tid & 63;
  const int wave = tid >> 6;
  const int wm = (wave & 1) * 64, wn = (wave >> 1) * 64;

  const unsigned short* pA = A + b * sA + (long)tm * BM * Kin;
  const unsigned short* pB = B + b * sB + (long)tn * BN * Kin;
  float* pC = C + b * sC;

  const int c0 = tid, c1 = tid + 256;
  const long ga0 = (long)(c0 >> 2) * Kin + (c0 & 3) * 8;
  const long ga1 = (long)(c1 >> 2) * Kin + (c1 & 3) * 8;

  f32x4 acc[4][4];
#pragma unroll
  for (int i = 0; i < 4; ++i)
#pragma unroll
    for (int j = 0; j < 4; ++j)
#pragma unroll
      for (int r = 0; r < 4; ++r) acc[i][j][r] = 0.f;

  const int mrow = wm + (lane & 15);
  const int nrow = wn + (lane & 15);
  const int kq = (lane >> 4) * 8;

  const int nk = Kin / BKK;
  for (int kt = 0; kt < nk; ++kt) {
    const long kb = (long)kt * BKK;
    __syncthreads();  // previous iter's LDS reads complete before overwrite
    ld16(pA + ga0 + kb, &sA_[c0 * 8]);
    ld16(pA + ga1 + kb, &sA_[c1 * 8]);
    ld16(pB + ga0 + kb, &sB_[c0 * 8]);
    ld16(pB + ga1 + kb, &sB_[c1 * 8]);
    __syncthreads();  // vmcnt drained before barrier -> LDS ready

    half8 af[4], bf[4];
#pragma unroll
    for (int i = 0; i < 4; ++i) {
      af[i] = *(const half8*)&sA_[(mrow + i * 16) * BKK + kq];
      bf[i] = *(const half8*)&sB_[(nrow + i * 16) * BKK + kq];
    }
#pragma unroll
    for (int i = 0; i < 4; ++i)
#pragma unroll
      for (int j = 0; j < 4; ++j)
        acc[i][j] = __builtin_amdgcn_mfma_f32_16x16x32_f16(af[i], bf[j], acc[i][j], 0, 0, 0);
  }

  const int crow0 = tm * BM + wm + (lane >> 4) * 4;
  const int ccol0 = tn * BN + wn + (lane & 15);
#pragma unroll
  for (int i = 0; i < 4; ++i)
#pragma unroll
    for (int j = 0; j < 4; ++j)
#pragma unroll
      for (int r = 0; r < 4; ++r)
        pC[(long)(crow0 + i * 16 + r) * N + (ccol0 + j * 16)] = acc[i][j][r];

  if constexpr (STATS) {
    // per-wave column stats over this wave's 64 rows; col = tn*BN+wn+j*16+(lane&15)
#pragma unroll
    for (int j = 0; j < 4; ++j) {
      float m = -3.0e38f;
#pragma unroll
      for (int i = 0; i < 4; ++i)
#pragma unroll
        for (int r = 0; r < 4; ++r) m = fmaxf(m, acc[i][j][r]);
      m = fmaxf(m, __shfl_xor(m, 16, 64));
      m = fmaxf(m, __shfl_xor(m, 32, 64));
      float l = 0.f;
#pragma unroll
      for (int i = 0; i < 4; ++i)
#pragma unroll
        for (int r = 0; r < 4; ++r) l += __expf(acc[i][j][r] - m);
      l += __shfl_xor(l, 16, 64);
      l += __shfl_xor(l, 32, 64);
      if (lane < 16) {
        int col = tn * BN + wn + j * 16 + lane;
        ps[((long)(b * 32 + tm * 2 + (wave & 1))) * N + col] = make_float2(m, l);
      }
    }
  }
}

// ---- combine 32 per-tile partials -> (M_k, 1/L_k) ----
__global__ void k_stats_combine(const float2* __restrict__ ps, float2* __restrict__ st, int Kn) {
  const long i = (long)blockIdx.x * blockDim.x + threadIdx.x;  // over nb*Kn
  const int b = (int)(i / Kn), k = (int)(i % Kn);
  float M = -3.0e38f;
#pragma unroll
  for (int j = 0; j < 32; ++j) M = fmaxf(M, ps[((long)(b * 32 + j)) * Kn + k].x);
  float L = 0.f;
#pragma unroll
  for (int j = 0; j < 32; ++j) {
    float2 v = ps[((long)(b * 32 + j)) * Kn + k];
    L += v.y * __expf(v.x - M);
  }
  st[i] = make_float2(M, 1.0f / L);
}

// ---- P = exp(S - M_k) * invL_k -> fp16, 8 elems/thread ----
__global__ void k_pcomp(const float* __restrict__ S, const float2* __restrict__ st,
                        unsigned short* __restrict__ P) {
  const long i = (long)blockIdx.x * blockDim.x + threadIdx.x;
  const long r = i >> 8;               // row = b*2048 + q  (2048/8 = 256 thr/row)
  const int kb = (int)(i & 255) * 8;
  const int b = (int)(r >> 11);
  const float* sp = S + r * 2048 + kb;
  float4 s0 = *(const float4*)sp;
  float4 s1 = *(const float4*)(sp + 4);
  const float2* tp = st + (long)b * 2048 + kb;
  us8 o;
  float sv[8] = {s0.x, s0.y, s0.z, s0.w, s1.x, s1.y, s1.z, s1.w};
#pragma unroll
  for (int j = 0; j < 8; ++j) {
    float2 t = tp[j];
    o[j] = f2h(__expf(sv[j] - t.x) * t.y);
  }
  *(us8*)(P + r * 2048 + kb) = o;
}

extern "C" void kernel_launch(void* const* d_in, const int* in_sizes, int n_in,
                              void* d_out, int out_size, void* d_ws, size_t ws_size,
                              hipStream_t stream) {
  const float* Q = (const float*)d_in[0];
  const float* Kp = (const float*)d_in[1];
  const float* V = (const float*)d_in[2];
  float* out = (float*)d_out;

  constexpr int Bb = 8, Qn = 2048, Kn = 2048, Dn = 1024;
  constexpr long QD = (long)Qn * Dn, KD = (long)Kn * Dn, QK = (long)Qn * Kn, DK = (long)Dn * Kn;

  // per-batch workspace need (bytes)
  const size_t per = 3 * (size_t)(QD * 2)   // q16, k16, vt
                   + (size_t)(QK * 4)       // S
                   + (size_t)(QK * 2)       // P
                   + (size_t)(32 * Kn * 8)  // partial stats (32 slots)
                   + (size_t)(Kn * 8);      // final stats
  int cb = 8;
  while (cb > 1 && (size_t)cb * per > ws_size) cb >>= 1;

  char* w = (char*)d_ws;
  unsigned short* q16 = (unsigned short*)w; w += (size_t)cb * QD * 2;
  unsigned short* k16 = (unsigned short*)w; w += (size_t)cb * KD * 2;
  unsigned short* vt  = (unsigned short*)w; w += (size_t)cb * DK * 2;
  float* S            = (float*)w;          w += (size_t)cb * QK * 4;
  unsigned short* P   = (unsigned short*)w; w += (size_t)cb * QK * 2;
  float2* ps          = (float2*)w;         w += (size_t)cb * 32 * Kn * 8;
  float2* st          = (float2*)w;

  for (int b0 = 0; b0 < Bb; b0 += cb) {
    int nb = (cb < Bb - b0) ? cb : (Bb - b0);
    long n8 = (long)nb * QD / 8;
    k_cast16<<<(int)(n8 / 256), 256, 0, stream>>>(Q + b0 * QD, q16, n8);
    k_cast16<<<(int)(n8 / 256), 256, 0, stream>>>(Kp + b0 * KD, k16, n8);
    k_transpose16<<<dim3(Kn / 64, Dn / 64, nb), 256, 0, stream>>>(V + b0 * KD, vt, Kn, Dn);
    k_gemm_bt<1><<<dim3(Kn / 128, Qn / 128, nb), 256, 0, stream>>>(
        q16, k16, S, ps, Kn, Dn, QD, KD, QK);
    k_stats_combine<<<nb * Kn / 256, 256, 0, stream>>>(ps, st, Kn);
    k_pcomp<<<(int)((long)nb * QK / 8 / 256), 256, 0, stream>>>(S, st, P);
    k_gemm_bt<0><<<dim3(Dn / 128, Qn / 128, nb), 256, 0, stream>>>(
        P, vt, out + b0 * QD, nullptr, Dn, Kn, QK, DK, QD);
  }
}